// Round 2
// baseline (761.342 us; speedup 1.0000x reference)
//
#include <hip/hip_runtime.h>
#include <stdint.h>

#define D 128
#define E_EDGES 600000
#define N_USER_C 100000
#define N_ITEM_C 50000
#define NEG_SLOPE 0.01f
#define LN_EPS 1e-5f

// Wt row pitch in shorts: 128 + 8 keeps rows 16B-aligned (272 B = 17*16) and
// gives row-stride of 4 banks -> b128 reads land 2-way max (free per m136).
#define LDPAD 136
#define BLOCKS_PER_REL 1024
#define WAVES_PER_REL (BLOCKS_PER_REL * 4)
#define N_WTILES (E_EDGES / 16)   // 37500 16-edge wave-tiles per relation

typedef __attribute__((ext_vector_type(8))) short bf16x8;
typedef __attribute__((ext_vector_type(4))) float f32x4;
typedef __attribute__((ext_vector_type(4))) uint32_t u32x4;

// fp32 -> bf16 round-to-nearest-even
__device__ inline short f2bf(float f) {
    uint32_t u = __builtin_bit_cast(uint32_t, f);
    u += 0x7fffu + ((u >> 16) & 1u);
    return (short)(u >> 16);
}
__device__ inline uint32_t pack2f(float a, float b) {
    return (uint32_t)(uint16_t)f2bf(a) | ((uint32_t)(uint16_t)f2bf(b) << 16);
}

// Both relations in one dispatch: blocks [0,BLOCKS_PER_REL) do user->item,
// the rest item->user. Per wave-tile (16 edges): gather A-fragments straight
// from global into registers (no P staging, no per-tile barriers), MFMA
// against LDS-resident W^T, then bias+LeakyReLU+atomicAdd scatter.
__global__ __launch_bounds__(256, 4) void ngcf_edge(
    const float* __restrict__ x_user, const float* __restrict__ x_item,
    const float* __restrict__ W_ui, const float* __restrict__ b_ui,
    const float* __restrict__ W_iu, const float* __restrict__ b_iu,
    const int* __restrict__ src_ui, const int* __restrict__ dst_ui,
    const int* __restrict__ src_iu, const int* __restrict__ dst_iu,
    float* __restrict__ agg_user, float* __restrict__ agg_item)
{
    __shared__ short Wt[128 * LDPAD];   // Wt[n][k] = W[k][n], bf16

    const int rel = (blockIdx.x >= BLOCKS_PER_REL) ? 1 : 0;
    const float* __restrict__ xsrc = rel ? x_item : x_user;
    const float* __restrict__ xdst = rel ? x_user : x_item;
    const float* __restrict__ W    = rel ? W_iu : W_ui;
    const float* __restrict__ bias = rel ? b_iu : b_ui;
    const int*   __restrict__ srci = rel ? src_iu : src_ui;
    const int*   __restrict__ dsti = rel ? dst_iu : dst_ui;
    float*       __restrict__ agg  = rel ? agg_user : agg_item;

    const int t = threadIdx.x;

    // Stage W^T (transpose + bf16 convert); reads coalesced.
    for (int i = t; i < 128 * 128; i += 256) {
        int k = i >> 7, n = i & 127;
        Wt[n * LDPAD + k] = f2bf(W[i]);
    }
    __syncthreads();   // the ONLY barrier — Wt is read-only afterwards

    const int wv   = t >> 6;
    const int l    = t & 63;
    const int lo16 = l & 15;
    const int quad = l >> 4;

    float bn[8];
    #pragma unroll
    for (int n = 0; n < 8; n++) bn[n] = bias[n * 16 + lo16];

    const int blk_in_rel = blockIdx.x - rel * BLOCKS_PER_REL;

    for (int wt = blk_in_rel * 4 + wv; wt < N_WTILES; wt += WAVES_PER_REL) {
        const int base = wt * 16;
        // each lane tracks edge base+lo16 (4-way redundant load, L1-hit)
        const int si = srci[base + lo16];
        const int di = dsti[base + lo16];
        const float* psrow = xsrc + ((size_t)si << 7);
        const float* pdrow = xdst + ((size_t)di << 7);

        f32x4 acc[8];
        #pragma unroll
        for (int n = 0; n < 8; n++) acc[n] = (f32x4){0.f, 0.f, 0.f, 0.f};

        #pragma unroll
        for (int kt = 0; kt < 4; kt++) {
            // lane (lo16,quad): k-slice [kt*32 + quad*8, +8) of its edge's rows
            const float4* ps = (const float4*)psrow + (kt * 8 + quad * 2);
            const float4* pd = (const float4*)pdrow + (kt * 8 + quad * 2);
            float4 a0 = ps[0], a1 = ps[1];
            float4 c0 = pd[0], c1 = pd[1];
            u32x4 up;
            up[0] = pack2f(a0.x * c0.x, a0.y * c0.y);
            up[1] = pack2f(a0.z * c0.z, a0.w * c0.w);
            up[2] = pack2f(a1.x * c1.x, a1.y * c1.y);
            up[3] = pack2f(a1.z * c1.z, a1.w * c1.w);
            bf16x8 afrag = __builtin_bit_cast(bf16x8, up);
            #pragma unroll
            for (int n = 0; n < 8; n++) {
                bf16x8 bfrag = *(const bf16x8*)&Wt[(n * 16 + lo16) * LDPAD + kt * 32 + quad * 8];
                acc[n] = __builtin_amdgcn_mfma_f32_16x16x32_bf16(afrag, bfrag, acc[n], 0, 0, 0);
            }
        }

        // epilogue: bias + LeakyReLU + scatter. C/D: col=n*16+lo16, row=quad*4+r.
        #pragma unroll
        for (int r = 0; r < 4; r++) {
            const int m = quad * 4 + r;
            const int drow = __shfl(di, m);   // dst of edge base+m (lane m holds it)
            float* p = agg + ((size_t)drow << 7) + lo16;
            #pragma unroll
            for (int n = 0; n < 8; n++) {
                float v = acc[n][r] + bn[n];
                v = v > 0.f ? v : NEG_SLOPE * v;
                atomicAdd(p + n * 16, v);   // imm-offset n*64B
            }
        }
    }
}

// In-place LayerNorm(mode=node) + ReLU. One wave per row, 2 floats/lane.
__global__ __launch_bounds__(256) void ln_relu(
    float* __restrict__ data,
    const float* __restrict__ lnw_u, const float* __restrict__ lnb_u,
    const float* __restrict__ lnw_i, const float* __restrict__ lnb_i,
    int n_user, int n_total)
{
    const int row = blockIdx.x * 4 + (threadIdx.x >> 6);
    if (row >= n_total) return;
    const int l = threadIdx.x & 63;

    float* rp = data + (size_t)row * D;
    float2 v = *(float2*)(rp + l * 2);
    float s  = v.x + v.y;
    float sq = v.x * v.x + v.y * v.y;
    #pragma unroll
    for (int off = 32; off > 0; off >>= 1) {
        s  += __shfl_xor(s, off);
        sq += __shfl_xor(sq, off);
    }
    const float mu  = s * (1.0f / 128.0f);
    const float var = sq * (1.0f / 128.0f) - mu * mu;
    const float rs  = rsqrtf(var + LN_EPS);

    const float* wgt = (row < n_user) ? lnw_u : lnw_i;
    const float* bia = (row < n_user) ? lnb_u : lnb_i;
    float2 wv2 = *(const float2*)(wgt + l * 2);
    float2 bv2 = *(const float2*)(bia + l * 2);

    float o0 = (v.x - mu) * rs * wv2.x + bv2.x;
    float o1 = (v.y - mu) * rs * wv2.y + bv2.y;
    *(float2*)(rp + l * 2) = make_float2(fmaxf(o0, 0.f), fmaxf(o1, 0.f));
}

extern "C" void kernel_launch(void* const* d_in, const int* in_sizes, int n_in,
                              void* d_out, int out_size, void* d_ws, size_t ws_size,
                              hipStream_t stream) {
    const float* x_user    = (const float*)d_in[0];
    const float* x_item    = (const float*)d_in[1];
    const float* W_ui      = (const float*)d_in[2];
    const float* b_ui      = (const float*)d_in[3];
    const float* W_iu      = (const float*)d_in[4];
    const float* b_iu      = (const float*)d_in[5];
    const float* ln_w_user = (const float*)d_in[6];
    const float* ln_b_user = (const float*)d_in[7];
    const float* ln_w_item = (const float*)d_in[8];
    const float* ln_b_item = (const float*)d_in[9];
    const int* esrc_ui = (const int*)d_in[10];
    const int* edst_ui = (const int*)d_in[11];
    const int* esrc_iu = (const int*)d_in[12];
    const int* edst_iu = (const int*)d_in[13];

    float* out = (float*)d_out;
    float* agg_user = out;                          // N_USER x D
    float* agg_item = out + (size_t)N_USER_C * D;   // N_ITEM x D

    hipMemsetAsync(d_out, 0, (size_t)out_size * sizeof(float), stream);

    ngcf_edge<<<dim3(2 * BLOCKS_PER_REL), dim3(256), 0, stream>>>(
        x_user, x_item, W_ui, b_ui, W_iu, b_iu,
        esrc_ui, edst_ui, esrc_iu, edst_iu, agg_user, agg_item);

    const int n_total = N_USER_C + N_ITEM_C;
    ln_relu<<<dim3((n_total + 3) / 4), dim3(256), 0, stream>>>(
        out, ln_w_user, ln_b_user, ln_w_item, ln_b_item, N_USER_C, n_total);
}